// Round 6
// baseline (594.159 us; speedup 1.0000x reference)
//
#include <hip/hip_runtime.h>
#include <math.h>

#define NN 50000
#define NE 1600000
#define DF 256
#define NBUCK 391   // ceil(NN/128); bucket = dst >> 7

typedef unsigned short ushortT;
typedef __attribute__((ext_vector_type(8))) short short8;
typedef __attribute__((ext_vector_type(4))) float floatx4;

__device__ __forceinline__ unsigned bf16rne(float f) {
    unsigned u = __float_as_uint(f);
    return (u + 0x7fffu + ((u >> 16) & 1u)) >> 16;
}

#define ASYNC16(gptr, ldsptr) \
    __builtin_amdgcn_global_load_lds((const __attribute__((address_space(1))) unsigned*)(gptr), \
                                     (__attribute__((address_space(3))) unsigned*)(ldsptr), 16, 0, 0)

// ---------------- CSR build via bucket binning ----------------

__global__ void k_zero(int* __restrict__ bcnt) {
    int i = blockIdx.x * 256 + threadIdx.x;
    if (i < NBUCK) bcnt[i] = 0;
}

__global__ __launch_bounds__(256)
void k_bhist(const int* __restrict__ dst, int* __restrict__ bcnt) {
    __shared__ int h[NBUCK];
    for (int i = threadIdx.x; i < NBUCK; i += 256) h[i] = 0;
    __syncthreads();
    int base = blockIdx.x * 4096;
#pragma unroll
    for (int i = 0; i < 16; ++i) {
        int e = base + i * 256 + threadIdx.x;
        if (e < NE) atomicAdd(&h[dst[e] >> 7], 1);
    }
    __syncthreads();
    for (int i = threadIdx.x; i < NBUCK; i += 256)
        if (h[i]) atomicAdd(&bcnt[i], h[i]);
}

__global__ void k_bscan(const int* __restrict__ bcnt, int* __restrict__ bbase,
                        int* __restrict__ cursor, int* __restrict__ row_ptr,
                        float* __restrict__ nrm) {
    __shared__ int s[512];
    int t = threadIdx.x;
    int v = (t < NBUCK) ? bcnt[t] : 0;
    s[t] = v; __syncthreads();
    for (int off = 1; off < 512; off <<= 1) {
        int x = (t >= off) ? s[t - off] : 0;
        __syncthreads();
        s[t] += x;
        __syncthreads();
    }
    if (t < NBUCK) { bbase[t] = s[t] - v; cursor[t] = s[t] - v; }
    if (t == 0) { bbase[NBUCK] = NE; row_ptr[NN] = NE; *nrm = 0.0f; }
}

__global__ __launch_bounds__(256)
void k_bin(const int* __restrict__ src, const int* __restrict__ dst,
           int* __restrict__ cursor, unsigned* __restrict__ rec) {
    __shared__ int h[NBUCK];
    __shared__ int gb[NBUCK];
    for (int i = threadIdx.x; i < NBUCK; i += 256) h[i] = 0;
    __syncthreads();
    const int base = blockIdx.x * 2048;
    int bk[8], rk[8];
    unsigned pk[8];
#pragma unroll
    for (int i = 0; i < 8; ++i) {
        int e = base + i * 256 + threadIdx.x;
        if (e < NE) {
            int d = dst[e];
            bk[i] = d >> 7;
            pk[i] = (unsigned)src[e] | ((unsigned)(d & 127) << 16);
            rk[i] = atomicAdd(&h[bk[i]], 1);
        } else bk[i] = -1;
    }
    __syncthreads();
    for (int i = threadIdx.x; i < NBUCK; i += 256) {
        int c = h[i];
        gb[i] = c ? atomicAdd(&cursor[i], c) : 0;
    }
    __syncthreads();
#pragma unroll
    for (int i = 0; i < 8; ++i)
        if (bk[i] >= 0) rec[gb[bk[i]] + rk[i]] = pk[i];
}

__global__ __launch_bounds__(256)
void k_csr(const unsigned* __restrict__ rec, const int* __restrict__ bbase,
           int* __restrict__ row_ptr, ushortT* __restrict__ csr) {
    __shared__ int cnt[128];
    __shared__ int cur[128];
    __shared__ int s[256];
    const int B = blockIdx.x, t = threadIdx.x;
    if (t < 128) cnt[t] = 0;
    __syncthreads();
    const int beg = bbase[B], end = bbase[B + 1];
    for (int p = beg + t; p < end; p += 256)
        atomicAdd(&cnt[(rec[p] >> 16) & 127], 1);
    __syncthreads();
    int v = (t < 128) ? cnt[t] : 0;
    s[t] = v; __syncthreads();
    for (int off = 1; off < 256; off <<= 1) {
        int x = (t >= off) ? s[t - off] : 0;
        __syncthreads();
        s[t] += x;
        __syncthreads();
    }
    if (t < 128) {
        int ex = s[t] - v;
        cur[t] = ex;
        int node = B * 128 + t;
        if (node < NN) row_ptr[node] = beg + ex;
    }
    __syncthreads();
    for (int p = beg + t; p < end; p += 256) {
        unsigned r = rec[p];
        int loc = atomicAdd(&cur[(r >> 16) & 127], 1);
        csr[beg + loc] = (ushortT)r;
    }
}

// ---------------- conversions ----------------

__global__ __launch_bounds__(256)
void k_cvt_emb(const float* __restrict__ emb, const int* __restrict__ gather,
               ushortT* __restrict__ out) {
    long long i = ((long long)blockIdx.x * 256 + threadIdx.x) * 8;
    int row = (int)(i >> 8);
    int col = (int)(i & 255);
    long long g = (long long)gather[row] * 256 + col;
    float4 v0 = *(const float4*)(emb + g);
    float4 v1 = *(const float4*)(emb + g + 4);
    uint4 o;
    o.x = bf16rne(v0.x) | (bf16rne(v0.y) << 16);
    o.y = bf16rne(v0.z) | (bf16rne(v0.w) << 16);
    o.z = bf16rne(v1.x) | (bf16rne(v1.y) << 16);
    o.w = bf16rne(v1.z) | (bf16rne(v1.w) << 16);
    *(uint4*)(out + i) = o;
}

__global__ __launch_bounds__(256)
void k_cvt_w(const float* __restrict__ Ws, const float* __restrict__ Wn,
             ushortT* __restrict__ Wt) {
    int idx = blockIdx.x * 256 + threadIdx.x;
    int n = idx >> 9;
    int k = idx & 511;
    float v = (k < 256) ? Ws[k * 256 + n] : Wn[(k - 256) * 256 + n];
    Wt[idx] = (ushortT)bf16rne(v);
}

// ---------------- neighbor mean aggregation (XCD column-sliced) ----------------
// slice = blockIdx & 7 -> XCD round-robin; each XCD touches a 3.2 MB column
// slice of feat (L2-resident). wave = one node: lanes = 8 edge-subgroups x
// 8 B of columns; 16 edges (2 rounds) in flight; shuffle-reduce subgroups.

__global__ __launch_bounds__(256)
void k_agg(const ushortT* __restrict__ feat, const int* __restrict__ row_ptr,
           const ushortT* __restrict__ csr, ushortT* __restrict__ out) {
    const int s = blockIdx.x & 7;                        // slice -> XCD
    const int node = (blockIdx.x >> 3) * 4 + (threadIdx.x >> 6);
    const int lane = threadIdx.x & 63;
    const int es = lane >> 3;                            // edge subgroup 0..7
    const int cbase = s * 32 + (lane & 7) * 4;           // ushort col offset

    const int beg = row_ptr[node], end = row_ptr[node + 1];
    float a0 = 0.f, a1 = 0.f, a2 = 0.f, a3 = 0.f;

#define ACC8(q) do { \
        a0 += __uint_as_float(q.x << 16); \
        a1 += __uint_as_float(q.x & 0xffff0000u); \
        a2 += __uint_as_float(q.y << 16); \
        a3 += __uint_as_float(q.y & 0xffff0000u); \
    } while (0)

    int p = beg;
    for (; p + 16 <= end; p += 16) {
        const int r0 = (int)csr[p + es] * DF + cbase;
        const int r1 = (int)csr[p + 8 + es] * DF + cbase;
        const uint2 q0 = *(const uint2*)(feat + r0);
        const uint2 q1 = *(const uint2*)(feat + r1);
        ACC8(q0); ACC8(q1);
    }
    if (p + 8 <= end) {
        const int r0 = (int)csr[p + es] * DF + cbase;
        const uint2 q0 = *(const uint2*)(feat + r0);
        ACC8(q0);
        p += 8;
    }
    const int rem = end - p;
    if (es < rem) {
        const int r0 = (int)csr[p + es] * DF + cbase;
        const uint2 q0 = *(const uint2*)(feat + r0);
        ACC8(q0);
    }
#undef ACC8

    // reduce across the 8 edge-subgroups (strides 32,16,8)
    a0 += __shfl_down(a0, 32); a1 += __shfl_down(a1, 32);
    a2 += __shfl_down(a2, 32); a3 += __shfl_down(a3, 32);
    a0 += __shfl_down(a0, 16); a1 += __shfl_down(a1, 16);
    a2 += __shfl_down(a2, 16); a3 += __shfl_down(a3, 16);
    a0 += __shfl_down(a0, 8);  a1 += __shfl_down(a1, 8);
    a2 += __shfl_down(a2, 8);  a3 += __shfl_down(a3, 8);

    if (es == 0) {
        const float inv = 1.0f / fmaxf((float)(end - beg), 1.0f);
        const unsigned lo = bf16rne(a0 * inv) | (bf16rne(a1 * inv) << 16);
        const unsigned hi = bf16rne(a2 * inv) | (bf16rne(a3 * inv) << 16);
        const unsigned long long v = (unsigned long long)lo | ((unsigned long long)hi << 32);
        __builtin_nontemporal_store(v, (unsigned long long*)(out + (long long)node * DF + cbase));
    }
}

// ---------------- fused dual GEMM, bf16 MFMA ----------------

template<int RELU, int NORM>
__global__ __launch_bounds__(256, 3)
void k_gemm(const ushortT* __restrict__ Aself, const ushortT* __restrict__ Aneigh,
            const ushortT* __restrict__ Wt, const float* __restrict__ bias,
            ushortT* __restrict__ Cb, float* __restrict__ Cf, float* __restrict__ norm_acc) {
    __shared__ ushortT As[4096];
    __shared__ ushortT Bs[4096];
    __shared__ float red[4];

    const int t = threadIdx.x;
    const int w = t >> 6;
    const int lane = t & 63;
    const int m0 = blockIdx.x * 128;
    const int n0 = blockIdx.y * 128;

    const int r0 = t >> 2;
    const int cu = (t & 3) * 8;

    const long long gA0 = (long long)min(m0 + r0, NN - 1) * 256;
    const long long gA1 = (long long)min(m0 + r0 + 64, NN - 1) * 256;
    const long long gB0 = (long long)(n0 + r0) * 512;
    const long long gB1 = (long long)(n0 + r0 + 64) * 512;

    const unsigned lds0 = w * 512;
    const unsigned lds1 = 2048 + w * 512;

    const int wm = w & 1, wn = w >> 1;
    const int fm = lane & 15;
    const int fk = (lane >> 4) * 8;

    floatx4 acc[4][4];
#pragma unroll
    for (int i = 0; i < 4; ++i)
#pragma unroll
        for (int j = 0; j < 4; ++j) acc[i][j] = (floatx4){0.f, 0.f, 0.f, 0.f};

    for (int kt = 0; kt < 512; kt += 32) {
        const ushortT* Ab; int kc;
        if (kt < 256) { Ab = Aself; kc = kt; } else { Ab = Aneigh; kc = kt - 256; }

        __syncthreads();
        ASYNC16(Ab + gA0 + kc + cu, As + lds0);
        ASYNC16(Ab + gA1 + kc + cu, As + lds1);
        ASYNC16(Wt + gB0 + kt + cu, Bs + lds0);
        ASYNC16(Wt + gB1 + kt + cu, Bs + lds1);
        __syncthreads();

        short8 af[4], bf[4];
#pragma unroll
        for (int i = 0; i < 4; ++i)
            af[i] = *(const short8*)&As[(wm * 64 + i * 16 + fm) * 32 + fk];
#pragma unroll
        for (int j = 0; j < 4; ++j)
            bf[j] = *(const short8*)&Bs[(wn * 64 + j * 16 + fm) * 32 + fk];
#pragma unroll
        for (int i = 0; i < 4; ++i)
#pragma unroll
            for (int j = 0; j < 4; ++j)
                acc[i][j] = __builtin_amdgcn_mfma_f32_16x16x32_bf16(af[i], bf[j], acc[i][j], 0, 0, 0);
    }

    float bj[4];
#pragma unroll
    for (int j = 0; j < 4; ++j) bj[j] = bias[n0 + wn * 64 + j * 16 + fm];

    float sumsq = 0.0f;
#pragma unroll
    for (int i = 0; i < 4; ++i) {
#pragma unroll
        for (int r = 0; r < 4; ++r) {
            const int row = m0 + wm * 64 + i * 16 + (lane >> 4) * 4 + r;
            if (row < NN) {
#pragma unroll
                for (int j = 0; j < 4; ++j) {
                    const int col = n0 + wn * 64 + j * 16 + fm;
                    float v = acc[i][j][r] + bj[j];
                    if (RELU) v = fmaxf(v, 0.0f);
                    if (NORM) {
                        Cf[(long long)row * 256 + col] = v;
                        sumsq += v * v;
                    } else {
                        Cb[(long long)row * 256 + col] = (ushortT)bf16rne(v);
                    }
                }
            }
        }
    }

    if (NORM) {
#pragma unroll
        for (int off = 32; off > 0; off >>= 1) sumsq += __shfl_down(sumsq, off);
        if (lane == 0) red[w] = sumsq;
        __syncthreads();
        if (t == 0) atomicAdd(norm_acc, red[0] + red[1] + red[2] + red[3]);
    }
}

__global__ void k_scale(float* __restrict__ out, const float* __restrict__ nrm) {
    const float s = 1.0f / sqrtf(*nrm);
    long long i = ((long long)blockIdx.x * 256 + threadIdx.x) * 4;
    float4 v = *(float4*)&out[i];
    v.x *= s; v.y *= s; v.z *= s; v.w *= s;
    *(float4*)&out[i] = v;
}

// ---------------- launch ----------------

extern "C" void kernel_launch(void* const* d_in, const int* in_sizes, int n_in,
                              void* d_out, int out_size, void* d_ws, size_t ws_size,
                              hipStream_t stream) {
    const int*   input_nodes = (const int*)d_in[0];
    const int*   esrc = (const int*)d_in[1];
    const int*   edst = (const int*)d_in[2];
    const float* emb  = (const float*)d_in[3];
    const float* Ws0  = (const float*)d_in[4];
    const float* Wn0  = (const float*)d_in[5];
    const float* b0   = (const float*)d_in[6];
    const float* Ws1  = (const float*)d_in[7];
    const float* Wn1  = (const float*)d_in[8];
    const float* b1   = (const float*)d_in[9];
    float* out = (float*)d_out;

    char* base = (char*)d_ws;
    ushortT*  embb    = (ushortT*) (base);                  // 25,600,000
    ushortT*  h1b     = (ushortT*) (base + 25600000);       // 25,600,000
    ushortT*  hnb     = (ushortT*) (base + 51200000);       // 25,600,000
    unsigned* rec     = (unsigned*)(base + 76800000);       //  6,400,000
    ushortT*  csr     = (ushortT*) (base + 83200000);       //  3,200,000
    ushortT*  Wt0     = (ushortT*) (base + 86400000);       //    262,144
    ushortT*  Wt1     = (ushortT*) (base + 86662144);       //    262,144
    int*      row_ptr = (int*)     (base + 86924288);       //    200,016
    int*      bcnt    = (int*)     (base + 87124304);       //      1,600
    int*      bbase   = (int*)     (base + 87125904);       //      1,600
    int*      cursor  = (int*)     (base + 87127504);       //      1,600
    float*    nrm     = (float*)   (base + 87129104);       //          4

    k_zero  <<<2,     256, 0, stream>>>(bcnt);
    k_bhist <<<391,   256, 0, stream>>>(edst, bcnt);
    k_bscan <<<1,     512, 0, stream>>>(bcnt, bbase, cursor, row_ptr, nrm);
    k_bin   <<<782,   256, 0, stream>>>(esrc, edst, cursor, rec);
    k_csr   <<<NBUCK, 256, 0, stream>>>(rec, bbase, row_ptr, csr);

    k_cvt_emb<<<NN * DF / 8 / 256, 256, 0, stream>>>(emb, input_nodes, embb);
    k_cvt_w  <<<512, 256, 0, stream>>>(Ws0, Wn0, Wt0);
    k_cvt_w  <<<512, 256, 0, stream>>>(Ws1, Wn1, Wt1);

    dim3 gg((NN + 127) / 128, 2);
    const int AGG_BLOCKS = (NN / 4) * 8;   // 100000: 12500 node-groups x 8 slices

    // layer 0
    k_agg<<<AGG_BLOCKS, 256, 0, stream>>>(embb, row_ptr, csr, hnb);
    k_gemm<1, 0><<<gg, 256, 0, stream>>>(embb, hnb, Wt0, b0, h1b, nullptr, nullptr);

    // layer 1
    k_agg<<<AGG_BLOCKS, 256, 0, stream>>>(h1b, row_ptr, csr, hnb);
    k_gemm<0, 1><<<gg, 256, 0, stream>>>(h1b, hnb, Wt1, b1, nullptr, out, nrm);

    k_scale<<<NN * DF / 4 / 256, 256, 0, stream>>>(out, nrm);
}

// Round 7
// 467.725 us; speedup vs baseline: 1.2703x; 1.2703x over previous
//
#include <hip/hip_runtime.h>
#include <math.h>

#define NN 50000
#define NE 1600000
#define DF 256
#define NBUCK 391   // ceil(NN/128); bucket = dst >> 7

typedef unsigned short ushortT;
typedef __attribute__((ext_vector_type(8))) short short8;
typedef __attribute__((ext_vector_type(4))) float floatx4;

__device__ __forceinline__ unsigned bf16rne(float f) {
    unsigned u = __float_as_uint(f);
    return (u + 0x7fffu + ((u >> 16) & 1u)) >> 16;
}

#define ASYNC16(gptr, ldsptr) \
    __builtin_amdgcn_global_load_lds((const __attribute__((address_space(1))) unsigned*)(gptr), \
                                     (__attribute__((address_space(3))) unsigned*)(ldsptr), 16, 0, 0)

// ---------------- CSR build via bucket binning ----------------

__global__ void k_zero(int* __restrict__ bcnt) {
    int i = blockIdx.x * 256 + threadIdx.x;
    if (i < NBUCK) bcnt[i] = 0;
}

__global__ __launch_bounds__(256)
void k_bhist(const int* __restrict__ dst, int* __restrict__ bcnt) {
    __shared__ int h[NBUCK];
    for (int i = threadIdx.x; i < NBUCK; i += 256) h[i] = 0;
    __syncthreads();
    int base = blockIdx.x * 4096;
#pragma unroll
    for (int i = 0; i < 16; ++i) {
        int e = base + i * 256 + threadIdx.x;
        if (e < NE) atomicAdd(&h[dst[e] >> 7], 1);
    }
    __syncthreads();
    for (int i = threadIdx.x; i < NBUCK; i += 256)
        if (h[i]) atomicAdd(&bcnt[i], h[i]);
}

__global__ void k_bscan(const int* __restrict__ bcnt, int* __restrict__ bbase,
                        int* __restrict__ cursor, int* __restrict__ row_ptr,
                        float* __restrict__ nrm) {
    __shared__ int s[512];
    int t = threadIdx.x;
    int v = (t < NBUCK) ? bcnt[t] : 0;
    s[t] = v; __syncthreads();
    for (int off = 1; off < 512; off <<= 1) {
        int x = (t >= off) ? s[t - off] : 0;
        __syncthreads();
        s[t] += x;
        __syncthreads();
    }
    if (t < NBUCK) { bbase[t] = s[t] - v; cursor[t] = s[t] - v; }
    if (t == 0) { bbase[NBUCK] = NE; row_ptr[NN] = NE; *nrm = 0.0f; }
}

__global__ __launch_bounds__(256)
void k_bin(const int* __restrict__ src, const int* __restrict__ dst,
           int* __restrict__ cursor, unsigned* __restrict__ rec) {
    __shared__ int h[NBUCK];
    __shared__ int gb[NBUCK];
    for (int i = threadIdx.x; i < NBUCK; i += 256) h[i] = 0;
    __syncthreads();
    const int base = blockIdx.x * 2048;
    int bk[8], rk[8];
    unsigned pk[8];
#pragma unroll
    for (int i = 0; i < 8; ++i) {
        int e = base + i * 256 + threadIdx.x;
        if (e < NE) {
            int d = dst[e];
            bk[i] = d >> 7;
            pk[i] = (unsigned)src[e] | ((unsigned)(d & 127) << 16);
            rk[i] = atomicAdd(&h[bk[i]], 1);
        } else bk[i] = -1;
    }
    __syncthreads();
    for (int i = threadIdx.x; i < NBUCK; i += 256) {
        int c = h[i];
        gb[i] = c ? atomicAdd(&cursor[i], c) : 0;
    }
    __syncthreads();
#pragma unroll
    for (int i = 0; i < 8; ++i)
        if (bk[i] >= 0) rec[gb[bk[i]] + rk[i]] = pk[i];
}

__global__ __launch_bounds__(256)
void k_csr(const unsigned* __restrict__ rec, const int* __restrict__ bbase,
           int* __restrict__ row_ptr, ushortT* __restrict__ csr) {
    __shared__ int cnt[128];
    __shared__ int cur[128];
    __shared__ int s[256];
    const int B = blockIdx.x, t = threadIdx.x;
    if (t < 128) cnt[t] = 0;
    __syncthreads();
    const int beg = bbase[B], end = bbase[B + 1];
    for (int p = beg + t; p < end; p += 256)
        atomicAdd(&cnt[(rec[p] >> 16) & 127], 1);
    __syncthreads();
    int v = (t < 128) ? cnt[t] : 0;
    s[t] = v; __syncthreads();
    for (int off = 1; off < 256; off <<= 1) {
        int x = (t >= off) ? s[t - off] : 0;
        __syncthreads();
        s[t] += x;
        __syncthreads();
    }
    if (t < 128) {
        int ex = s[t] - v;
        cur[t] = ex;
        int node = B * 128 + t;
        if (node < NN) row_ptr[node] = beg + ex;
    }
    __syncthreads();
    for (int p = beg + t; p < end; p += 256) {
        unsigned r = rec[p];
        int loc = atomicAdd(&cur[(r >> 16) & 127], 1);
        csr[beg + loc] = (ushortT)r;
    }
}

// ---------------- conversions (merged) ----------------
// blocks [0,6250): emb gather+cvt; [6250,6762): Wt0; [6762,7274): Wt1

__global__ __launch_bounds__(256)
void k_cvt(const float* __restrict__ emb, const int* __restrict__ gather,
           ushortT* __restrict__ embb,
           const float* __restrict__ Ws0, const float* __restrict__ Wn0,
           ushortT* __restrict__ Wt0,
           const float* __restrict__ Ws1, const float* __restrict__ Wn1,
           ushortT* __restrict__ Wt1) {
    const int b = blockIdx.x;
    if (b < 6250) {
        long long i = ((long long)b * 256 + threadIdx.x) * 8;
        int row = (int)(i >> 8);
        int col = (int)(i & 255);
        long long g = (long long)gather[row] * 256 + col;
        float4 v0 = *(const float4*)(emb + g);
        float4 v1 = *(const float4*)(emb + g + 4);
        uint4 o;
        o.x = bf16rne(v0.x) | (bf16rne(v0.y) << 16);
        o.y = bf16rne(v0.z) | (bf16rne(v0.w) << 16);
        o.z = bf16rne(v1.x) | (bf16rne(v1.y) << 16);
        o.w = bf16rne(v1.z) | (bf16rne(v1.w) << 16);
        *(uint4*)(embb + i) = o;
    } else {
        const bool first = b < 6762;
        const int idx = ((first ? b - 6250 : b - 6762)) * 256 + threadIdx.x;
        const int n = idx >> 9;
        const int k = idx & 511;
        const float* Ws = first ? Ws0 : Ws1;
        const float* Wn = first ? Wn0 : Wn1;
        float v = (k < 256) ? Ws[k * 256 + n] : Wn[(k - 256) * 256 + n];
        (first ? Wt0 : Wt1)[idx] = (ushortT)bf16rne(v);
    }
}

// ---------------- neighbor mean aggregation (bf16, MLP=4; R3-proven) ----------------

__global__ __launch_bounds__(256)
void k_agg(const ushortT* __restrict__ feat, const int* __restrict__ row_ptr,
           const ushortT* __restrict__ csr, ushortT* __restrict__ out) {
    int node = blockIdx.x * 4 + (threadIdx.x >> 6);
    int lane = threadIdx.x & 63;
    int half = lane >> 5;
    int l5 = lane & 31;
    if (node >= NN) return;
    int beg = row_ptr[node], end = row_ptr[node + 1];

    float s[8] = {0.f, 0.f, 0.f, 0.f, 0.f, 0.f, 0.f, 0.f};
    int p = beg + half;

#define ACCUM(q) do { \
        s[0] += __uint_as_float(q.x << 16); \
        s[1] += __uint_as_float(q.x & 0xffff0000u); \
        s[2] += __uint_as_float(q.y << 16); \
        s[3] += __uint_as_float(q.y & 0xffff0000u); \
        s[4] += __uint_as_float(q.z << 16); \
        s[5] += __uint_as_float(q.z & 0xffff0000u); \
        s[6] += __uint_as_float(q.w << 16); \
        s[7] += __uint_as_float(q.w & 0xffff0000u); \
    } while (0)

    for (; p + 6 < end; p += 8) {
        int r0 = (int)csr[p]     * DF + l5 * 8;
        int r1 = (int)csr[p + 2] * DF + l5 * 8;
        int r2 = (int)csr[p + 4] * DF + l5 * 8;
        int r3 = (int)csr[p + 6] * DF + l5 * 8;
        uint4 a = *(const uint4*)(feat + r0);
        uint4 b = *(const uint4*)(feat + r1);
        uint4 c = *(const uint4*)(feat + r2);
        uint4 d = *(const uint4*)(feat + r3);
        ACCUM(a); ACCUM(b); ACCUM(c); ACCUM(d);
    }
    for (; p < end; p += 2) {
        int r0 = (int)csr[p] * DF + l5 * 8;
        uint4 a = *(const uint4*)(feat + r0);
        ACCUM(a);
    }
#undef ACCUM

#pragma unroll
    for (int k = 0; k < 8; ++k) s[k] += __shfl_down(s[k], 32);

    if (half == 0) {
        float inv = 1.0f / fmaxf((float)(end - beg), 1.0f);
        uint4 o;
        o.x = bf16rne(s[0] * inv) | (bf16rne(s[1] * inv) << 16);
        o.y = bf16rne(s[2] * inv) | (bf16rne(s[3] * inv) << 16);
        o.z = bf16rne(s[4] * inv) | (bf16rne(s[5] * inv) << 16);
        o.w = bf16rne(s[6] * inv) | (bf16rne(s[7] * inv) << 16);
        *(uint4*)(out + (long long)node * DF + l5 * 8) = o;
    }
}

// ---------------- dual GEMM, M-split 64x256 tile ----------------
// block = 64 rows x all 256 cols; A-slab read ONCE (vs twice with N-split).
// K=512 concat: kt<256 self, else neigh. W (256KB) is L2-resident.

template<int RELU, int NORM>
__global__ __launch_bounds__(256, 4)
void k_gemm(const ushortT* __restrict__ Aself, const ushortT* __restrict__ Aneigh,
            const ushortT* __restrict__ Wt, const float* __restrict__ bias,
            ushortT* __restrict__ Cb, float* __restrict__ Cf, float* __restrict__ norm_acc) {
    __shared__ ushortT As[2048];   // [64 m][32 k]
    __shared__ ushortT Bs[8192];   // [256 n][32 k]
    __shared__ float red[4];

    const int t = threadIdx.x;
    const int w = t >> 6;
    const int lane = t & 63;
    const int m0 = blockIdx.x * 64;

    const int ar = t >> 2;        // row within tile (0..63)
    const int cu = (t & 3) * 8;   // ushort offset within 32-elem k-row

    const long long gA = (long long)min(m0 + ar, NN - 1) * 256;

    const unsigned ldsA = w * 512;   // + lane*8 by HW
    const unsigned ldsB = w * 512;

    const int fm = lane & 15;
    const int fk = (lane >> 4) * 8;

    floatx4 acc[4][4];
#pragma unroll
    for (int i = 0; i < 4; ++i)
#pragma unroll
        for (int j = 0; j < 4; ++j) acc[i][j] = (floatx4){0.f, 0.f, 0.f, 0.f};

    for (int kt = 0; kt < 512; kt += 32) {
        const ushortT* Ab; int kc;
        if (kt < 256) { Ab = Aself; kc = kt; } else { Ab = Aneigh; kc = kt - 256; }

        __syncthreads();
        ASYNC16(Ab + gA + kc + cu, As + ldsA);
#pragma unroll
        for (int i = 0; i < 4; ++i)
            ASYNC16(Wt + (i * 64 + ar) * 512 + kt + cu, Bs + i * 2048 + ldsB);
        __syncthreads();

        short8 af[4], bf[4];
#pragma unroll
        for (int i = 0; i < 4; ++i)
            af[i] = *(const short8*)&As[(i * 16 + fm) * 32 + fk];
#pragma unroll
        for (int j = 0; j < 4; ++j)
            bf[j] = *(const short8*)&Bs[(w * 64 + j * 16 + fm) * 32 + fk];
#pragma unroll
        for (int i = 0; i < 4; ++i)
#pragma unroll
            for (int j = 0; j < 4; ++j)
                acc[i][j] = __builtin_amdgcn_mfma_f32_16x16x32_bf16(af[i], bf[j], acc[i][j], 0, 0, 0);
    }

    float bj[4];
#pragma unroll
    for (int j = 0; j < 4; ++j) bj[j] = bias[w * 64 + j * 16 + fm];

    float sumsq = 0.0f;
#pragma unroll
    for (int i = 0; i < 4; ++i) {
#pragma unroll
        for (int r = 0; r < 4; ++r) {
            const int row = m0 + i * 16 + (lane >> 4) * 4 + r;
            if (row < NN) {
#pragma unroll
                for (int j = 0; j < 4; ++j) {
                    const int col = w * 64 + j * 16 + fm;
                    float v = acc[i][j][r] + bj[j];
                    if (RELU) v = fmaxf(v, 0.0f);
                    if (NORM) {
                        Cf[(long long)row * 256 + col] = v;
                        sumsq += v * v;
                    } else {
                        Cb[(long long)row * 256 + col] = (ushortT)bf16rne(v);
                    }
                }
            }
        }
    }

    if (NORM) {
#pragma unroll
        for (int off = 32; off > 0; off >>= 1) sumsq += __shfl_down(sumsq, off);
        if (lane == 0) red[w] = sumsq;
        __syncthreads();
        if (t == 0) atomicAdd(norm_acc, red[0] + red[1] + red[2] + red[3]);
    }
}

__global__ void k_scale(float* __restrict__ out, const float* __restrict__ nrm) {
    const float s = 1.0f / sqrtf(*nrm);
    long long i = ((long long)blockIdx.x * 256 + threadIdx.x) * 4;
    float4 v = *(float4*)&out[i];
    v.x *= s; v.y *= s; v.z *= s; v.w *= s;
    *(float4*)&out[i] = v;
}

// ---------------- launch ----------------

extern "C" void kernel_launch(void* const* d_in, const int* in_sizes, int n_in,
                              void* d_out, int out_size, void* d_ws, size_t ws_size,
                              hipStream_t stream) {
    const int*   input_nodes = (const int*)d_in[0];
    const int*   esrc = (const int*)d_in[1];
    const int*   edst = (const int*)d_in[2];
    const float* emb  = (const float*)d_in[3];
    const float* Ws0  = (const float*)d_in[4];
    const float* Wn0  = (const float*)d_in[5];
    const float* b0   = (const float*)d_in[6];
    const float* Ws1  = (const float*)d_in[7];
    const float* Wn1  = (const float*)d_in[8];
    const float* b1   = (const float*)d_in[9];
    float* out = (float*)d_out;

    char* base = (char*)d_ws;
    ushortT*  embb    = (ushortT*) (base);                  // 25,600,000
    ushortT*  h1b     = (ushortT*) (base + 25600000);       // 25,600,000
    ushortT*  hnb     = (ushortT*) (base + 51200000);       // 25,600,000
    unsigned* rec     = (unsigned*)(base + 76800000);       //  6,400,000
    ushortT*  csr     = (ushortT*) (base + 83200000);       //  3,200,000
    ushortT*  Wt0     = (ushortT*) (base + 86400000);       //    262,144
    ushortT*  Wt1     = (ushortT*) (base + 86662144);       //    262,144
    int*      row_ptr = (int*)     (base + 86924288);       //    200,016
    int*      bcnt    = (int*)     (base + 87124304);       //      1,600
    int*      bbase   = (int*)     (base + 87125904);       //      1,600
    int*      cursor  = (int*)     (base + 87127504);       //      1,600
    float*    nrm     = (float*)   (base + 87129104);       //          4

    k_zero  <<<2,     256, 0, stream>>>(bcnt);
    k_bhist <<<391,   256, 0, stream>>>(edst, bcnt);
    k_bscan <<<1,     512, 0, stream>>>(bcnt, bbase, cursor, row_ptr, nrm);
    k_bin   <<<782,   256, 0, stream>>>(esrc, edst, cursor, rec);
    k_csr   <<<NBUCK, 256, 0, stream>>>(rec, bbase, row_ptr, csr);

    k_cvt<<<7274, 256, 0, stream>>>(emb, input_nodes, embb, Ws0, Wn0, Wt0, Ws1, Wn1, Wt1);

    const int GEMM_BLOCKS = (NN + 63) / 64;   // 782

    // layer 0
    k_agg<<<NN / 4, 256, 0, stream>>>(embb, row_ptr, csr, hnb);
    k_gemm<1, 0><<<GEMM_BLOCKS, 256, 0, stream>>>(embb, hnb, Wt0, b0, h1b, nullptr, nullptr);

    // layer 1
    k_agg<<<NN / 4, 256, 0, stream>>>(h1b, row_ptr, csr, hnb);
    k_gemm<0, 1><<<GEMM_BLOCKS, 256, 0, stream>>>(h1b, hnb, Wt1, b1, nullptr, out, nrm);

    k_scale<<<NN * DF / 4 / 256, 256, 0, stream>>>(out, nrm);
}